// Round 18
// baseline (198.841 us; speedup 1.0000x reference)
//
#include <hip/hip_runtime.h>
#include <hip/hip_fp16.h>
#include <math.h>

#define N_NODES 100000
#define N_EDGES 3200000
#define F_IN    128
#define F_HID   32
#define F_OUT   40
#define NBINS   ((N_NODES + 255) >> 8)   // 391 coarse bins of 256 nodes
#define EPB     4096                     // edges per block in partition pass A
#define NBLK    ((N_EDGES + EPB - 1) / EPB)
#define SRC_SPLIT 50000
#define CAPH    (N_EDGES / 2 + 8 * N_NODES)   // per-half bucket capacity
#define NCLS    64

typedef _Float16 h2_t __attribute__((ext_vector_type(2)));
__device__ __forceinline__ float fdot2u(unsigned a, unsigned b, float c) {
    return __builtin_amdgcn_fdot2(__builtin_bit_cast(h2_t, a),
                                  __builtin_bit_cast(h2_t, b), c, false);
}

// ---------------------------------------------------------------------------
// GEMM1: h1h[N,32] = fp16(x[N,128] @ W1[128,32])
// ---------------------------------------------------------------------------
__global__ __launch_bounds__(256) void gemm1_kernel(const float* __restrict__ x,
                                                    const float* __restrict__ W,
                                                    __half* __restrict__ h1h) {
    __shared__ float Ws[F_IN * F_HID];     // 16 KB
    __shared__ float Xs[32][F_IN + 4];
    const int tid  = threadIdx.x;
    const int row0 = blockIdx.x * 32;

    for (int i = tid; i < (F_IN * F_HID) / 4; i += 256)
        ((float4*)Ws)[i] = ((const float4*)W)[i];

    for (int i = tid; i < 1024; i += 256) {
        int r = i >> 5;
        int c = i & 31;
        ((float4*)&Xs[r][0])[c] = ((const float4*)x)[(size_t)(row0 + r) * (F_IN / 4) + c];
    }
    __syncthreads();

    const int r  = tid >> 3;
    const int c0 = (tid & 7) * 4;
    float a0 = 0.f, a1 = 0.f, a2 = 0.f, a3 = 0.f;
    for (int k = 0; k < F_IN; ++k) {
        const float xv = Xs[r][k];
        const float* wrow = &Ws[k * F_HID + c0];
        a0 += xv * wrow[0];
        a1 += xv * wrow[1];
        a2 += xv * wrow[2];
        a3 += xv * wrow[3];
    }
    const int row = row0 + r;   // grid exact: 3125*32 == N_NODES
    __half2* o = (__half2*)(h1h + (size_t)row * F_HID + c0);
    o[0] = __floats2half2_rn(a0, a1);
    o[1] = __floats2half2_rn(a2, a3);
}

// ---------------------------------------------------------------------------
// Stage 1: per-block bin histogram (LDS) -> gcnt[blk][bin].
// ---------------------------------------------------------------------------
__global__ __launch_bounds__(256) void histA_kernel(const int* __restrict__ ei,
                                                    int* __restrict__ gcnt) {
    __shared__ int lh[NBINS];
    const int tid = threadIdx.x;
    const int e0  = blockIdx.x * EPB;
    for (int i = tid; i < NBINS; i += 256) lh[i] = 0;
    __syncthreads();

    for (int base = 0; base < EPB; base += 1024) {
        const int e = e0 + base + 4 * tid;
        if (e + 3 < N_EDGES) {
            const int4 dv = *(const int4*)&ei[N_EDGES + e];
            atomicAdd(&lh[dv.x >> 8], 1);
            atomicAdd(&lh[dv.y >> 8], 1);
            atomicAdd(&lh[dv.z >> 8], 1);
            atomicAdd(&lh[dv.w >> 8], 1);
        } else {
            for (int k = 0; k < 4; ++k)
                if (e + k < N_EDGES) atomicAdd(&lh[ei[N_EDGES + e + k] >> 8], 1);
        }
    }
    __syncthreads();
    for (int b = tid; b < NBINS; b += 256)
        gcnt[(size_t)blockIdx.x * NBINS + b] = lh[b];
}

// ---------------------------------------------------------------------------
// Stage 2: per-bin column scan over blocks -> pbase[blk][bin] + bintot[bin].
// ---------------------------------------------------------------------------
__global__ __launch_bounds__(256) void colscan_kernel(const int* __restrict__ gcnt,
                                                      int* __restrict__ pbase,
                                                      int* __restrict__ bintot) {
    __shared__ int s[256];
    __shared__ int carry;
    const int b   = blockIdx.x;
    const int tid = threadIdx.x;
    if (tid == 0) carry = 0;
    __syncthreads();
    for (int c = 0; c < NBLK; c += 256) {
        const int blk = c + tid;
        const int v = (blk < NBLK) ? gcnt[(size_t)blk * NBINS + b] : 0;
        s[tid] = v;
        __syncthreads();
        for (int off = 1; off < 256; off <<= 1) {
            int u = (tid >= off) ? s[tid - off] : 0;
            __syncthreads();
            s[tid] += u;
            __syncthreads();
        }
        if (blk < NBLK) pbase[(size_t)blk * NBINS + b] = carry + s[tid] - v;
        __syncthreads();
        if (tid == 255) carry += s[255];
        __syncthreads();
    }
    if (tid == 0) bintot[b] = carry;
}

// ---------------------------------------------------------------------------
// Stage 3: exclusive scan over 391 bin totals -> binbase[0..NBINS].
// ---------------------------------------------------------------------------
__global__ __launch_bounds__(512) void binscan_kernel(const int* __restrict__ bintot,
                                                      int* __restrict__ binbase) {
    __shared__ int s[512];
    const int t = threadIdx.x;
    const int v = (t < NBINS) ? bintot[t] : 0;
    s[t] = v;
    __syncthreads();
    for (int off = 1; off < 512; off <<= 1) {
        int u = (t >= off) ? s[t - off] : 0;
        __syncthreads();
        s[t] += u;
        __syncthreads();
    }
    if (t <= NBINS) binbase[t] = s[t] - v;
}

// ---------------------------------------------------------------------------
// Stage 4: place. Bases = binbase + pbase (deterministic, no global atomics).
// Emits packed word (src|fp16w<<17) + meta ushort (dlow | srchalf<<8).
// ---------------------------------------------------------------------------
__global__ __launch_bounds__(256) void placeA_kernel(const int* __restrict__ ei,
                                                     const float* __restrict__ ew,
                                                     const int* __restrict__ gcnt,
                                                     const int* __restrict__ binbase,
                                                     const int* __restrict__ pbase,
                                                     int* __restrict__ stg4,
                                                     unsigned short* __restrict__ metag) {
    __shared__ int lhist[512];
    __shared__ int lscan[512];
    __shared__ int lcur[512];
    __shared__ int lwbase[512];
    __shared__ int stmp[256];
    __shared__ int lstg4[EPB];                 // 16 KB
    __shared__ unsigned short lbin[EPB];       // 8 KB
    __shared__ unsigned short lmeta[EPB];      // 8 KB
    const int tid = threadIdx.x;
    const int blk = blockIdx.x;
    const int e0  = blk * EPB;
    const int tot = min(EPB, N_EDGES - e0);

    lhist[tid] = 0; lhist[tid + 256] = 0;
    lwbase[tid] = 0; lwbase[tid + 256] = 0;
    __syncthreads();
    for (int b = tid; b < NBINS; b += 256) {
        lhist[b]  = gcnt[(size_t)blk * NBINS + b];
        lwbase[b] = binbase[b] + pbase[(size_t)blk * NBINS + b];
    }
    __syncthreads();

    const int ca = lhist[2 * tid];
    const int cb = lhist[2 * tid + 1];
    const int pair = ca + cb;
    stmp[tid] = pair;
    __syncthreads();
    for (int off = 1; off < 256; off <<= 1) {
        int u = (tid >= off) ? stmp[tid - off] : 0;
        __syncthreads();
        stmp[tid] += u;
        __syncthreads();
    }
    const int pexcl = stmp[tid] - pair;
    lscan[2 * tid]     = pexcl;
    lscan[2 * tid + 1] = pexcl + ca;
    lcur[2 * tid]      = pexcl;
    lcur[2 * tid + 1]  = pexcl + ca;
    __syncthreads();

#define PLACE1(S, D, WF)                                                        \
    {                                                                           \
        const int b = (D) >> 8;                                                 \
        const int p = atomicAdd(&lcur[b], 1);                                   \
        lstg4[p] = (S) | ((int)__half_as_ushort(__float2half(WF)) << 17);       \
        lbin[p] = (unsigned short)b;                                            \
        lmeta[p] = (unsigned short)(((D) & 255) | (((S) >= SRC_SPLIT) << 8));   \
    }
    for (int base = 0; base < EPB; base += 1024) {
        const int e = e0 + base + 4 * tid;
        if (e + 3 < N_EDGES) {
            const int4   sv = *(const int4*)&ei[e];
            const int4   dv = *(const int4*)&ei[N_EDGES + e];
            const float4 wv = *(const float4*)&ew[e];
            PLACE1(sv.x, dv.x, wv.x);
            PLACE1(sv.y, dv.y, wv.y);
            PLACE1(sv.z, dv.z, wv.z);
            PLACE1(sv.w, dv.w, wv.w);
        } else {
            for (int k = 0; k < 4; ++k)
                if (e + k < N_EDGES)
                    PLACE1(ei[e + k], ei[N_EDGES + e + k], ew[e + k]);
        }
    }
#undef PLACE1
    __syncthreads();

    for (int i = tid; i < tot; i += 256) {
        const int b = lbin[i];
        const int pos = lwbase[b] + (i - lscan[b]);
        stg4[pos] = lstg4[i];
        metag[pos] = lmeta[i];
    }
}

// ---------------------------------------------------------------------------
// Pass B1: per bin, count per-(node, src-half) degrees from meta, pad each
// to 8, in-LDS scans -> in-bin offsets (A and B) + padded bin totals.
// ---------------------------------------------------------------------------
__global__ __launch_bounds__(256) void partB1_kernel(const int* __restrict__ binbase,
                                                     const unsigned short* __restrict__ metag,
                                                     int* __restrict__ offsIBA,
                                                     int* __restrict__ offsIBB,
                                                     int* __restrict__ pbtA,
                                                     int* __restrict__ pbtB) {
    __shared__ int lcA[256], lcB[256], lsc[256];
    const int tid   = threadIdx.x;
    const int b     = blockIdx.x;
    const int start = binbase[b];
    const int end   = binbase[b + 1];

    lcA[tid] = 0; lcB[tid] = 0;
    __syncthreads();
    for (int j = start + tid; j < end; j += 256) {
        const unsigned m = metag[j];
        if (m & 256) atomicAdd(&lcB[m & 255], 1);
        else         atomicAdd(&lcA[m & 255], 1);
    }
    __syncthreads();

    const int padA = (lcA[tid] + 7) & ~7;
    lsc[tid] = padA;
    __syncthreads();
    for (int off = 1; off < 256; off <<= 1) {
        int u = (tid >= off) ? lsc[tid - off] : 0;
        __syncthreads();
        lsc[tid] += u;
        __syncthreads();
    }
    offsIBA[(b << 8) + tid] = lsc[tid] - padA;
    if (tid == 255) pbtA[b] = lsc[255];
    __syncthreads();

    const int padB = (lcB[tid] + 7) & ~7;
    lsc[tid] = padB;
    __syncthreads();
    for (int off = 1; off < 256; off <<= 1) {
        int u = (tid >= off) ? lsc[tid - off] : 0;
        __syncthreads();
        lsc[tid] += u;
        __syncthreads();
    }
    offsIBB[(b << 8) + tid] = lsc[tid] - padB;
    if (tid == 255) pbtB[b] = lsc[255];
}

// ---------------------------------------------------------------------------
// Scans over padded bin totals (A then B) -> pbbA/pbbB; offsX[N] = totals.
// ---------------------------------------------------------------------------
__global__ __launch_bounds__(512) void padscan2_kernel(const int* __restrict__ pbtA,
                                                       const int* __restrict__ pbtB,
                                                       int* __restrict__ pbbA,
                                                       int* __restrict__ pbbB,
                                                       int* __restrict__ offsA,
                                                       int* __restrict__ offsB) {
    __shared__ int s[512];
    const int t = threadIdx.x;
    {
        const int v = (t < NBINS) ? pbtA[t] : 0;
        s[t] = v;
        __syncthreads();
        for (int off = 1; off < 512; off <<= 1) {
            int u = (t >= off) ? s[t - off] : 0;
            __syncthreads();
            s[t] += u;
            __syncthreads();
        }
        if (t <= NBINS) pbbA[t] = s[t] - v;
        if (t == NBINS) offsA[N_NODES] = s[t] - v;
        __syncthreads();
    }
    {
        const int v = (t < NBINS) ? pbtB[t] : 0;
        s[t] = v;
        __syncthreads();
        for (int off = 1; off < 512; off <<= 1) {
            int u = (t >= off) ? s[t - off] : 0;
            __syncthreads();
            s[t] += u;
            __syncthreads();
        }
        if (t <= NBINS) pbbB[t] = s[t] - v;
        if (t == NBINS) offsB[N_NODES] = s[t] - v;
    }
}

// ---------------------------------------------------------------------------
// Pass B2: route words to bktA/bktB by src-half; write offsA/offsB[node];
// pads: bktA -> 0 (row 0), bktB -> SRC_SPLIT (in-slice row, w=0).
// ---------------------------------------------------------------------------
__global__ __launch_bounds__(256) void partB2_kernel(const int* __restrict__ binbase,
                                                     const int* __restrict__ stg4,
                                                     const unsigned short* __restrict__ metag,
                                                     const int* __restrict__ pbbA,
                                                     const int* __restrict__ pbbB,
                                                     const int* __restrict__ offsIBA,
                                                     const int* __restrict__ offsIBB,
                                                     int* __restrict__ offsA,
                                                     int* __restrict__ offsB,
                                                     int* __restrict__ bktA,
                                                     int* __restrict__ bktB) {
    __shared__ int lcurA[256], lcurB[256];
    const int tid  = threadIdx.x;
    const int b    = blockIdx.x;
    const int node = (b << 8) + tid;
    const int baseA = pbbA[b] + offsIBA[node];
    const int baseB = pbbB[b] + offsIBB[node];
    const int pendA = (tid < 255) ? (pbbA[b] + offsIBA[node + 1]) : pbbA[b + 1];
    const int pendB = (tid < 255) ? (pbbB[b] + offsIBB[node + 1]) : pbbB[b + 1];
    lcurA[tid] = baseA;
    lcurB[tid] = baseB;
    if (node < N_NODES) { offsA[node] = baseA; offsB[node] = baseB; }
    __syncthreads();

    const int start = binbase[b];
    const int end   = binbase[b + 1];
    for (int j = start + tid; j < end; j += 256) {
        const int word = stg4[j];
        const unsigned m = metag[j];
        if (m & 256) {
            const int pos = atomicAdd(&lcurB[m & 255], 1);
            bktB[pos] = word;
        } else {
            const int pos = atomicAdd(&lcurA[m & 255], 1);
            bktA[pos] = word;
        }
    }
    __syncthreads();

    for (int k = lcurA[tid]; k < pendA; ++k) bktA[k] = 0;
    for (int k = lcurB[tid]; k < pendB; ++k) bktB[k] = SRC_SPLIT;
}

// ---------------------------------------------------------------------------
// Degree-sort: class = min(paddedTotal/8, 63); counting sort -> perm.
// Output values are node-placement-invariant, so perm nondeterminism is OK.
// ---------------------------------------------------------------------------
__global__ __launch_bounds__(256) void deghist_kernel(const int* __restrict__ offsA,
                                                      const int* __restrict__ offsB,
                                                      int* __restrict__ dcnt) {
    __shared__ int lc[NCLS];
    const int tid = threadIdx.x;
    if (tid < NCLS) lc[tid] = 0;
    __syncthreads();
    const int n = blockIdx.x * 256 + tid;
    if (n < N_NODES) {
        const int len = (offsA[n + 1] - offsA[n]) + (offsB[n + 1] - offsB[n]);
        atomicAdd(&lc[min(len >> 3, NCLS - 1)], 1);
    }
    __syncthreads();
    if (tid < NCLS && lc[tid]) atomicAdd(&dcnt[tid], lc[tid]);
}

__global__ __launch_bounds__(64) void degscan_kernel(const int* __restrict__ dcnt,
                                                     int* __restrict__ dcur) {
    __shared__ int s[NCLS];
    const int t = threadIdx.x;
    const int v = dcnt[t];
    s[t] = v;
    __syncthreads();
    for (int off = 1; off < NCLS; off <<= 1) {
        int u = (t >= off) ? s[t - off] : 0;
        __syncthreads();
        s[t] += u;
        __syncthreads();
    }
    dcur[t] = s[t] - v;
}

__global__ __launch_bounds__(256) void degplace_kernel(const int* __restrict__ offsA,
                                                       const int* __restrict__ offsB,
                                                       int* __restrict__ dcur,
                                                       int* __restrict__ perm) {
    __shared__ int lcnt[NCLS], lbase[NCLS];
    const int tid = threadIdx.x;
    if (tid < NCLS) lcnt[tid] = 0;
    __syncthreads();
    const int n = blockIdx.x * 256 + tid;
    int cls = 0;
    if (n < N_NODES) {
        const int len = (offsA[n + 1] - offsA[n]) + (offsB[n + 1] - offsB[n]);
        cls = min(len >> 3, NCLS - 1);
        atomicAdd(&lcnt[cls], 1);
    }
    __syncthreads();
    if (tid < NCLS) {
        const int c = lcnt[tid];
        lbase[tid] = c ? atomicAdd(&dcur[tid], c) : 0;
        lcnt[tid] = 0;
    }
    __syncthreads();
    if (n < N_NODES) {
        const int r = atomicAdd(&lcnt[cls], 1);
        perm[lbase[cls] + r] = n;
    }
}

// ---------------------------------------------------------------------------
// Group-per-node gather core: 8 lanes own one node; lane sub holds features
// 4*sub..4*sub+3. Segment [j, jend) is a multiple of 8 (pad words: w=0).
// ---------------------------------------------------------------------------
__device__ __forceinline__ void gather_grp(const int* __restrict__ bkt,
                                           int j, const int jend,
                                           const char* __restrict__ tbl,
                                           const unsigned sub8,
                                           float& a0, float& a1, float& a2, float& a3) {
#define PAIR_BODY(PX, PY, RA, RB)                                               \
    {                                                                           \
        const unsigned wp = __builtin_amdgcn_perm((unsigned)(PY) >> 17,         \
                                                  (unsigned)(PX) >> 17,         \
                                                  0x05040100u);                 \
        a0 = fdot2u(__builtin_amdgcn_perm((RB).x, (RA).x, 0x05040100u), wp, a0);\
        a1 = fdot2u(__builtin_amdgcn_perm((RB).x, (RA).x, 0x07060302u), wp, a1);\
        a2 = fdot2u(__builtin_amdgcn_perm((RB).y, (RA).y, 0x05040100u), wp, a2);\
        a3 = fdot2u(__builtin_amdgcn_perm((RB).y, (RA).y, 0x07060302u), wp, a3);\
    }
#define TBL(P) (*(const uint2*)(tbl + (((unsigned)(P) & 0x1FFFFu) << 6) + sub8))
    for (; j < jend; j += 8) {
        const int4 p0 = *(const int4*)&bkt[j];       // broadcast within group
        const int4 p1 = *(const int4*)&bkt[j + 4];
        const uint2 r0 = TBL(p0.x);
        const uint2 r1 = TBL(p0.y);
        const uint2 r2 = TBL(p0.z);
        const uint2 r3 = TBL(p0.w);
        const uint2 r4 = TBL(p1.x);
        const uint2 r5 = TBL(p1.y);
        const uint2 r6 = TBL(p1.z);
        const uint2 r7 = TBL(p1.w);
        PAIR_BODY(p0.x, p0.y, r0, r1);
        PAIR_BODY(p0.z, p0.w, r2, r3);
        PAIR_BODY(p1.x, p1.y, r4, r5);
        PAIR_BODY(p1.z, p1.w, r6, r7);
    }
#undef TBL
#undef PAIR_BODY
}

// ---------------------------------------------------------------------------
// Gather 1 + bias1 + ReLU (degree-sorted nodes, A-half then B-half).
// ---------------------------------------------------------------------------
__global__ __launch_bounds__(256) void gather1_kernel(const int* __restrict__ perm,
                                                      const int* __restrict__ offsA,
                                                      const int* __restrict__ offsB,
                                                      const int* __restrict__ bktA,
                                                      const int* __restrict__ bktB,
                                                      const __half* __restrict__ h1h,
                                                      const float* __restrict__ b1,
                                                      __half* __restrict__ rh) {
    const int tid  = threadIdx.x;
    const int node = perm[blockIdx.x * 32 + (tid >> 3)];   // grid exact: 3125*32
    const int sub  = tid & 7;
    const unsigned sub8 = sub * 8;

    float a0 = 0.f, a1 = 0.f, a2 = 0.f, a3 = 0.f;
    gather_grp(bktA, offsA[node], offsA[node + 1], (const char*)h1h, sub8,
               a0, a1, a2, a3);
    gather_grp(bktB, offsB[node], offsB[node + 1], (const char*)h1h, sub8,
               a0, a1, a2, a3);

    const float4 bb = ((const float4*)b1)[sub];
    a0 = fmaxf(a0 + bb.x, 0.f);
    a1 = fmaxf(a1 + bb.y, 0.f);
    a2 = fmaxf(a2 + bb.z, 0.f);
    a3 = fmaxf(a3 + bb.w, 0.f);
    uint2 o;
    *(__half2*)&o.x = __floats2half2_rn(a0, a1);
    *(__half2*)&o.y = __floats2half2_rn(a2, a3);
    *(uint2*)((char*)rh + (size_t)node * 64 + sub8) = o;
}

// ---------------------------------------------------------------------------
// Gather 2 (A,B) + W2 + bias2 + log-softmax, fused, degree-sorted.
// ---------------------------------------------------------------------------
__global__ __launch_bounds__(256) void gather2_lsm_kernel(const int* __restrict__ perm,
                                                          const int* __restrict__ offsA,
                                                          const int* __restrict__ offsB,
                                                          const int* __restrict__ bktA,
                                                          const int* __restrict__ bktB,
                                                          const __half* __restrict__ rh,
                                                          const float* __restrict__ W2,
                                                          const float* __restrict__ b2,
                                                          float* __restrict__ out) {
    __shared__ float W2s[F_HID * F_OUT];   // 5 KB
    __shared__ float sblk[32][F_HID + 1];  // 4.2 KB
    const int tid = threadIdx.x;
    for (int i = tid; i < F_HID * F_OUT; i += 256) W2s[i] = W2[i];
    __syncthreads();

    const int nn   = tid >> 3;
    const int node = perm[blockIdx.x * 32 + nn];           // grid exact: 3125*32
    const int sub  = tid & 7;
    const unsigned sub8 = sub * 8;

    float a0 = 0.f, a1 = 0.f, a2 = 0.f, a3 = 0.f;
    gather_grp(bktA, offsA[node], offsA[node + 1], (const char*)rh, sub8,
               a0, a1, a2, a3);
    gather_grp(bktB, offsB[node], offsB[node + 1], (const char*)rh, sub8,
               a0, a1, a2, a3);

    // stash the node's 32-dim sum (group-local; same-wave ordering suffices)
    sblk[nn][sub * 4 + 0] = a0;
    sblk[nn][sub * 4 + 1] = a1;
    sblk[nn][sub * 4 + 2] = a2;
    sblk[nn][sub * 4 + 3] = a3;

    // transform: lane computes outputs sub, sub+8, ..., sub+32
    float o0 = b2[sub], o1 = b2[sub + 8], o2 = b2[sub + 16],
          o3 = b2[sub + 24], o4 = b2[sub + 32];
    #pragma unroll
    for (int k = 0; k < F_HID; ++k) {
        const float sv = sblk[nn][k];
        const float* wr = &W2s[k * F_OUT + sub];
        o0 += sv * wr[0];
        o1 += sv * wr[8];
        o2 += sv * wr[16];
        o3 += sv * wr[24];
        o4 += sv * wr[32];
    }

    // group softmax over 40 values (5 per lane x 8 lanes)
    float m = fmaxf(fmaxf(fmaxf(o0, o1), fmaxf(o2, o3)), o4);
    m = fmaxf(m, __shfl_xor(m, 1));
    m = fmaxf(m, __shfl_xor(m, 2));
    m = fmaxf(m, __shfl_xor(m, 4));
    float ex = __expf(o0 - m) + __expf(o1 - m) + __expf(o2 - m)
             + __expf(o3 - m) + __expf(o4 - m);
    ex += __shfl_xor(ex, 1);
    ex += __shfl_xor(ex, 2);
    ex += __shfl_xor(ex, 4);
    const float ls = m + __logf(ex);

    float* op = out + (size_t)node * F_OUT + sub;
    op[0]  = o0 - ls;
    op[8]  = o1 - ls;
    op[16] = o2 - ls;
    op[24] = o3 - ls;
    op[32] = o4 - ls;
}

// ---------------------------------------------------------------------------
extern "C" void kernel_launch(void* const* d_in, const int* in_sizes, int n_in,
                              void* d_out, int out_size, void* d_ws, size_t ws_size,
                              hipStream_t stream) {
    const float* x  = (const float*)d_in[0];
    const int*   ei = (const int*)d_in[1];    // [2, E] int32: row 0 = src, row 1 = dst
    const float* ew = (const float*)d_in[2];
    const float* W1 = (const float*)d_in[3];
    const float* b1 = (const float*)d_in[4];
    const float* W2 = (const float*)d_in[5];
    const float* b2 = (const float*)d_in[6];
    float* out = (float*)d_out;

    // Workspace layout (16B-aligned), ~44 MB total.
    char* p = (char*)d_ws;
    size_t off = 0;
    auto alloc = [&](size_t bytes) {
        char* r = p + off;
        off += (bytes + 15) & ~(size_t)15;
        return r;
    };
    int*   gcnt    = (int*)  alloc((size_t)NBLK * NBINS * 4);
    int*   pbase   = (int*)  alloc((size_t)NBLK * NBINS * 4);
    int*   bintot  = (int*)  alloc((size_t)NBINS * 4);
    int*   binbase = (int*)  alloc((size_t)(NBINS + 1) * 4);
    int*   pbtA    = (int*)  alloc((size_t)NBINS * 4);
    int*   pbtB    = (int*)  alloc((size_t)NBINS * 4);
    int*   pbbA    = (int*)  alloc((size_t)(NBINS + 1) * 4);
    int*   pbbB    = (int*)  alloc((size_t)(NBINS + 1) * 4);
    int*   dcnt    = (int*)  alloc((size_t)NCLS * 4);
    int*   dcur    = (int*)  alloc((size_t)NCLS * 4);
    int*   offsIBA = (int*)  alloc((size_t)NBINS * 256 * 4);
    int*   offsIBB = (int*)  alloc((size_t)NBINS * 256 * 4);
    int*   offsA   = (int*)  alloc((size_t)(N_NODES + 1) * 4);
    int*   offsB   = (int*)  alloc((size_t)(N_NODES + 1) * 4);
    int*   perm    = (int*)  alloc((size_t)N_NODES * 4);
    int*   bktA    = (int*)  alloc((size_t)CAPH * 4);
    int*   bktB    = (int*)  alloc((size_t)CAPH * 4);
    char*  uni     = (char*) alloc((size_t)N_EDGES * 6);   // stg4 + meta ushort
    int*   stg4    = (int*)uni;
    unsigned short* metag = (unsigned short*)(uni + (size_t)N_EDGES * 4);
    __half* h1h    = (__half*)uni;
    __half* rh     = h1h + (size_t)N_NODES * F_HID;

    const int nnodeblk = (N_NODES + 255) / 256;   // 391

    // --- CSR build (deterministic bases, no global atomics) ---
    histA_kernel<<<NBLK, 256, 0, stream>>>(ei, gcnt);
    colscan_kernel<<<NBINS, 256, 0, stream>>>(gcnt, pbase, bintot);
    binscan_kernel<<<1, 512, 0, stream>>>(bintot, binbase);
    placeA_kernel<<<NBLK, 256, 0, stream>>>(ei, ew, gcnt, binbase, pbase, stg4, metag);
    partB1_kernel<<<NBINS, 256, 0, stream>>>(binbase, metag, offsIBA, offsIBB, pbtA, pbtB);
    padscan2_kernel<<<1, 512, 0, stream>>>(pbtA, pbtB, pbbA, pbbB, offsA, offsB);
    partB2_kernel<<<NBINS, 256, 0, stream>>>(binbase, stg4, metag, pbbA, pbbB,
                                             offsIBA, offsIBB, offsA, offsB, bktA, bktB);

    // --- Degree-sorted node permutation (wave load balance) ---
    hipMemsetAsync(dcnt, 0, NCLS * 4, stream);
    deghist_kernel<<<nnodeblk, 256, 0, stream>>>(offsA, offsB, dcnt);
    degscan_kernel<<<1, 64, 0, stream>>>(dcnt, dcur);
    degplace_kernel<<<nnodeblk, 256, 0, stream>>>(offsA, offsB, dcur, perm);

    // --- Layer 1: h1 = x@W1 (fp16 table); gather A-half then B-half ---
    gemm1_kernel<<<N_NODES / 32, 256, 0, stream>>>(x, W1, h1h);
    gather1_kernel<<<N_NODES / 32, 256, 0, stream>>>(perm, offsA, offsB, bktA, bktB, h1h, b1, rh);

    // --- Layer 2: gather (A,B) + W2 + bias2 + log-softmax, fused ---
    gather2_lsm_kernel<<<N_NODES / 32, 256, 0, stream>>>(perm, offsA, offsB, bktA, bktB, rh, W2, b2, out);
}

// Round 19
// 172.094 us; speedup vs baseline: 1.1554x; 1.1554x over previous
//
#include <hip/hip_runtime.h>
#include <hip/hip_fp16.h>
#include <math.h>

#define N_NODES 100000
#define N_EDGES 3200000
#define F_IN    128
#define F_HID   32
#define F_OUT   40
#define NBINS   ((N_NODES + 255) >> 8)   // 391 coarse bins of 256 nodes
#define EPB     4096                     // edges per block in partition pass A
#define NBLK    ((N_EDGES + EPB - 1) / EPB)
#define SRC_SPLIT 50000
#define CAPH    (N_EDGES / 2 + 8 * N_NODES)   // per-half bucket capacity

typedef _Float16 h2_t __attribute__((ext_vector_type(2)));
__device__ __forceinline__ float fdot2u(unsigned a, unsigned b, float c) {
    return __builtin_amdgcn_fdot2(__builtin_bit_cast(h2_t, a),
                                  __builtin_bit_cast(h2_t, b), c, false);
}

// ---------------------------------------------------------------------------
// GEMM1: h1h[N,32] = fp16(x[N,128] @ W1[128,32])
// ---------------------------------------------------------------------------
__global__ __launch_bounds__(256) void gemm1_kernel(const float* __restrict__ x,
                                                    const float* __restrict__ W,
                                                    __half* __restrict__ h1h) {
    __shared__ float Ws[F_IN * F_HID];     // 16 KB
    __shared__ float Xs[32][F_IN + 4];
    const int tid  = threadIdx.x;
    const int row0 = blockIdx.x * 32;

    for (int i = tid; i < (F_IN * F_HID) / 4; i += 256)
        ((float4*)Ws)[i] = ((const float4*)W)[i];

    for (int i = tid; i < 1024; i += 256) {
        int r = i >> 5;
        int c = i & 31;
        ((float4*)&Xs[r][0])[c] = ((const float4*)x)[(size_t)(row0 + r) * (F_IN / 4) + c];
    }
    __syncthreads();

    const int r  = tid >> 3;
    const int c0 = (tid & 7) * 4;
    float a0 = 0.f, a1 = 0.f, a2 = 0.f, a3 = 0.f;
    for (int k = 0; k < F_IN; ++k) {
        const float xv = Xs[r][k];
        const float* wrow = &Ws[k * F_HID + c0];
        a0 += xv * wrow[0];
        a1 += xv * wrow[1];
        a2 += xv * wrow[2];
        a3 += xv * wrow[3];
    }
    const int row = row0 + r;   // grid exact: 3125*32 == N_NODES
    __half2* o = (__half2*)(h1h + (size_t)row * F_HID + c0);
    o[0] = __floats2half2_rn(a0, a1);
    o[1] = __floats2half2_rn(a2, a3);
}

// ---------------------------------------------------------------------------
// Stage 1: per-block bin histogram (LDS) -> gcnt[blk][bin].
// ---------------------------------------------------------------------------
__global__ __launch_bounds__(256) void histA_kernel(const int* __restrict__ ei,
                                                    int* __restrict__ gcnt) {
    __shared__ int lh[NBINS];
    const int tid = threadIdx.x;
    const int e0  = blockIdx.x * EPB;
    for (int i = tid; i < NBINS; i += 256) lh[i] = 0;
    __syncthreads();

    for (int base = 0; base < EPB; base += 1024) {
        const int e = e0 + base + 4 * tid;
        if (e + 3 < N_EDGES) {
            const int4 dv = *(const int4*)&ei[N_EDGES + e];
            atomicAdd(&lh[dv.x >> 8], 1);
            atomicAdd(&lh[dv.y >> 8], 1);
            atomicAdd(&lh[dv.z >> 8], 1);
            atomicAdd(&lh[dv.w >> 8], 1);
        } else {
            for (int k = 0; k < 4; ++k)
                if (e + k < N_EDGES) atomicAdd(&lh[ei[N_EDGES + e + k] >> 8], 1);
        }
    }
    __syncthreads();
    for (int b = tid; b < NBINS; b += 256)
        gcnt[(size_t)blockIdx.x * NBINS + b] = lh[b];
}

// ---------------------------------------------------------------------------
// Stage 2: per-bin column scan over blocks -> pbase[blk][bin] + bintot[bin].
// ---------------------------------------------------------------------------
__global__ __launch_bounds__(256) void colscan_kernel(const int* __restrict__ gcnt,
                                                      int* __restrict__ pbase,
                                                      int* __restrict__ bintot) {
    __shared__ int s[256];
    __shared__ int carry;
    const int b   = blockIdx.x;
    const int tid = threadIdx.x;
    if (tid == 0) carry = 0;
    __syncthreads();
    for (int c = 0; c < NBLK; c += 256) {
        const int blk = c + tid;
        const int v = (blk < NBLK) ? gcnt[(size_t)blk * NBINS + b] : 0;
        s[tid] = v;
        __syncthreads();
        for (int off = 1; off < 256; off <<= 1) {
            int u = (tid >= off) ? s[tid - off] : 0;
            __syncthreads();
            s[tid] += u;
            __syncthreads();
        }
        if (blk < NBLK) pbase[(size_t)blk * NBINS + b] = carry + s[tid] - v;
        __syncthreads();
        if (tid == 255) carry += s[255];
        __syncthreads();
    }
    if (tid == 0) bintot[b] = carry;
}

// ---------------------------------------------------------------------------
// Stage 3: exclusive scan over 391 bin totals -> binbase[0..NBINS].
// ---------------------------------------------------------------------------
__global__ __launch_bounds__(512) void binscan_kernel(const int* __restrict__ bintot,
                                                      int* __restrict__ binbase) {
    __shared__ int s[512];
    const int t = threadIdx.x;
    const int v = (t < NBINS) ? bintot[t] : 0;
    s[t] = v;
    __syncthreads();
    for (int off = 1; off < 512; off <<= 1) {
        int u = (t >= off) ? s[t - off] : 0;
        __syncthreads();
        s[t] += u;
        __syncthreads();
    }
    if (t <= NBINS) binbase[t] = s[t] - v;
}

// ---------------------------------------------------------------------------
// Stage 4: place. Bases = binbase + pbase (deterministic, no global atomics).
// Emits packed word (src|fp16w<<17) + meta ushort (dlow | srchalf<<8).
// ---------------------------------------------------------------------------
__global__ __launch_bounds__(256) void placeA_kernel(const int* __restrict__ ei,
                                                     const float* __restrict__ ew,
                                                     const int* __restrict__ gcnt,
                                                     const int* __restrict__ binbase,
                                                     const int* __restrict__ pbase,
                                                     int* __restrict__ stg4,
                                                     unsigned short* __restrict__ metag) {
    __shared__ int lhist[512];
    __shared__ int lscan[512];
    __shared__ int lcur[512];
    __shared__ int lwbase[512];
    __shared__ int stmp[256];
    __shared__ int lstg4[EPB];                 // 16 KB
    __shared__ unsigned short lbin[EPB];       // 8 KB
    __shared__ unsigned short lmeta[EPB];      // 8 KB
    const int tid = threadIdx.x;
    const int blk = blockIdx.x;
    const int e0  = blk * EPB;
    const int tot = min(EPB, N_EDGES - e0);

    lhist[tid] = 0; lhist[tid + 256] = 0;
    lwbase[tid] = 0; lwbase[tid + 256] = 0;
    __syncthreads();
    for (int b = tid; b < NBINS; b += 256) {
        lhist[b]  = gcnt[(size_t)blk * NBINS + b];
        lwbase[b] = binbase[b] + pbase[(size_t)blk * NBINS + b];
    }
    __syncthreads();

    const int ca = lhist[2 * tid];
    const int cb = lhist[2 * tid + 1];
    const int pair = ca + cb;
    stmp[tid] = pair;
    __syncthreads();
    for (int off = 1; off < 256; off <<= 1) {
        int u = (tid >= off) ? stmp[tid - off] : 0;
        __syncthreads();
        stmp[tid] += u;
        __syncthreads();
    }
    const int pexcl = stmp[tid] - pair;
    lscan[2 * tid]     = pexcl;
    lscan[2 * tid + 1] = pexcl + ca;
    lcur[2 * tid]      = pexcl;
    lcur[2 * tid + 1]  = pexcl + ca;
    __syncthreads();

#define PLACE1(S, D, WF)                                                        \
    {                                                                           \
        const int b = (D) >> 8;                                                 \
        const int p = atomicAdd(&lcur[b], 1);                                   \
        lstg4[p] = (S) | ((int)__half_as_ushort(__float2half(WF)) << 17);       \
        lbin[p] = (unsigned short)b;                                            \
        lmeta[p] = (unsigned short)(((D) & 255) | (((S) >= SRC_SPLIT) << 8));   \
    }
    for (int base = 0; base < EPB; base += 1024) {
        const int e = e0 + base + 4 * tid;
        if (e + 3 < N_EDGES) {
            const int4   sv = *(const int4*)&ei[e];
            const int4   dv = *(const int4*)&ei[N_EDGES + e];
            const float4 wv = *(const float4*)&ew[e];
            PLACE1(sv.x, dv.x, wv.x);
            PLACE1(sv.y, dv.y, wv.y);
            PLACE1(sv.z, dv.z, wv.z);
            PLACE1(sv.w, dv.w, wv.w);
        } else {
            for (int k = 0; k < 4; ++k)
                if (e + k < N_EDGES)
                    PLACE1(ei[e + k], ei[N_EDGES + e + k], ew[e + k]);
        }
    }
#undef PLACE1
    __syncthreads();

    for (int i = tid; i < tot; i += 256) {
        const int b = lbin[i];
        const int pos = lwbase[b] + (i - lscan[b]);
        stg4[pos] = lstg4[i];
        metag[pos] = lmeta[i];
    }
}

// ---------------------------------------------------------------------------
// Pass B1: per bin, count per-(node, src-half) degrees from meta (4-deep
// preloaded), pad each to 8, in-LDS scans -> in-bin offsets + padded totals.
// ---------------------------------------------------------------------------
__global__ __launch_bounds__(256) void partB1_kernel(const int* __restrict__ binbase,
                                                     const unsigned short* __restrict__ metag,
                                                     int* __restrict__ offsIBA,
                                                     int* __restrict__ offsIBB,
                                                     int* __restrict__ pbtA,
                                                     int* __restrict__ pbtB) {
    __shared__ int lcA[256], lcB[256], lsc[256];
    const int tid   = threadIdx.x;
    const int b     = blockIdx.x;
    const int start = binbase[b];
    const int end   = binbase[b + 1];

    lcA[tid] = 0; lcB[tid] = 0;
    __syncthreads();
    for (int j0 = start; j0 < end; j0 += 1024) {
        const int j = j0 + tid;
        unsigned m0 = 0, m1 = 0, m2 = 0, m3 = 0;
        const bool v0 = j < end, v1 = j + 256 < end,
                   v2 = j + 512 < end, v3 = j + 768 < end;
        if (v0) m0 = metag[j];
        if (v1) m1 = metag[j + 256];
        if (v2) m2 = metag[j + 512];
        if (v3) m3 = metag[j + 768];
        if (v0) { if (m0 & 256) atomicAdd(&lcB[m0 & 255], 1); else atomicAdd(&lcA[m0 & 255], 1); }
        if (v1) { if (m1 & 256) atomicAdd(&lcB[m1 & 255], 1); else atomicAdd(&lcA[m1 & 255], 1); }
        if (v2) { if (m2 & 256) atomicAdd(&lcB[m2 & 255], 1); else atomicAdd(&lcA[m2 & 255], 1); }
        if (v3) { if (m3 & 256) atomicAdd(&lcB[m3 & 255], 1); else atomicAdd(&lcA[m3 & 255], 1); }
    }
    __syncthreads();

    const int padA = (lcA[tid] + 7) & ~7;
    lsc[tid] = padA;
    __syncthreads();
    for (int off = 1; off < 256; off <<= 1) {
        int u = (tid >= off) ? lsc[tid - off] : 0;
        __syncthreads();
        lsc[tid] += u;
        __syncthreads();
    }
    offsIBA[(b << 8) + tid] = lsc[tid] - padA;
    if (tid == 255) pbtA[b] = lsc[255];
    __syncthreads();

    const int padB = (lcB[tid] + 7) & ~7;
    lsc[tid] = padB;
    __syncthreads();
    for (int off = 1; off < 256; off <<= 1) {
        int u = (tid >= off) ? lsc[tid - off] : 0;
        __syncthreads();
        lsc[tid] += u;
        __syncthreads();
    }
    offsIBB[(b << 8) + tid] = lsc[tid] - padB;
    if (tid == 255) pbtB[b] = lsc[255];
}

// ---------------------------------------------------------------------------
// Scans over padded bin totals (A then B) -> pbbA/pbbB; offsX[N] = totals.
// ---------------------------------------------------------------------------
__global__ __launch_bounds__(512) void padscan2_kernel(const int* __restrict__ pbtA,
                                                       const int* __restrict__ pbtB,
                                                       int* __restrict__ pbbA,
                                                       int* __restrict__ pbbB,
                                                       int* __restrict__ offsA,
                                                       int* __restrict__ offsB) {
    __shared__ int s[512];
    const int t = threadIdx.x;
    {
        const int v = (t < NBINS) ? pbtA[t] : 0;
        s[t] = v;
        __syncthreads();
        for (int off = 1; off < 512; off <<= 1) {
            int u = (t >= off) ? s[t - off] : 0;
            __syncthreads();
            s[t] += u;
            __syncthreads();
        }
        if (t <= NBINS) pbbA[t] = s[t] - v;
        if (t == NBINS) offsA[N_NODES] = s[t] - v;
        __syncthreads();
    }
    {
        const int v = (t < NBINS) ? pbtB[t] : 0;
        s[t] = v;
        __syncthreads();
        for (int off = 1; off < 512; off <<= 1) {
            int u = (t >= off) ? s[t - off] : 0;
            __syncthreads();
            s[t] += u;
            __syncthreads();
        }
        if (t <= NBINS) pbbB[t] = s[t] - v;
        if (t == NBINS) offsB[N_NODES] = s[t] - v;
    }
}

// ---------------------------------------------------------------------------
// Pass B2: route words to bktA/bktB by src-half (4-deep preloaded); write
// offsA/offsB[node]; pads: bktA -> 0, bktB -> SRC_SPLIT (in-slice, w=0).
// ---------------------------------------------------------------------------
__global__ __launch_bounds__(256) void partB2_kernel(const int* __restrict__ binbase,
                                                     const int* __restrict__ stg4,
                                                     const unsigned short* __restrict__ metag,
                                                     const int* __restrict__ pbbA,
                                                     const int* __restrict__ pbbB,
                                                     const int* __restrict__ offsIBA,
                                                     const int* __restrict__ offsIBB,
                                                     int* __restrict__ offsA,
                                                     int* __restrict__ offsB,
                                                     int* __restrict__ bktA,
                                                     int* __restrict__ bktB) {
    __shared__ int lcurA[256], lcurB[256];
    const int tid  = threadIdx.x;
    const int b    = blockIdx.x;
    const int node = (b << 8) + tid;
    const int baseA = pbbA[b] + offsIBA[node];
    const int baseB = pbbB[b] + offsIBB[node];
    const int pendA = (tid < 255) ? (pbbA[b] + offsIBA[node + 1]) : pbbA[b + 1];
    const int pendB = (tid < 255) ? (pbbB[b] + offsIBB[node + 1]) : pbbB[b + 1];
    lcurA[tid] = baseA;
    lcurB[tid] = baseB;
    if (node < N_NODES) { offsA[node] = baseA; offsB[node] = baseB; }
    __syncthreads();

    const int start = binbase[b];
    const int end   = binbase[b + 1];
#define ROUTE1(W, M)                                                            \
    {                                                                           \
        if ((M) & 256) { const int pos = atomicAdd(&lcurB[(M) & 255], 1); bktB[pos] = (W); } \
        else           { const int pos = atomicAdd(&lcurA[(M) & 255], 1); bktA[pos] = (W); } \
    }
    for (int j0 = start; j0 < end; j0 += 1024) {
        const int j = j0 + tid;
        int w0 = 0, w1 = 0, w2 = 0, w3 = 0;
        unsigned m0 = 0, m1 = 0, m2 = 0, m3 = 0;
        const bool v0 = j < end, v1 = j + 256 < end,
                   v2 = j + 512 < end, v3 = j + 768 < end;
        if (v0) { w0 = stg4[j];       m0 = metag[j]; }
        if (v1) { w1 = stg4[j + 256]; m1 = metag[j + 256]; }
        if (v2) { w2 = stg4[j + 512]; m2 = metag[j + 512]; }
        if (v3) { w3 = stg4[j + 768]; m3 = metag[j + 768]; }
        if (v0) ROUTE1(w0, m0);
        if (v1) ROUTE1(w1, m1);
        if (v2) ROUTE1(w2, m2);
        if (v3) ROUTE1(w3, m3);
    }
#undef ROUTE1
    __syncthreads();

    for (int k = lcurA[tid]; k < pendA; ++k) bktA[k] = 0;
    for (int k = lcurB[tid]; k < pendB; ++k) bktB[k] = SRC_SPLIT;
}

// ---------------------------------------------------------------------------
// Group-per-node gather core: 8 lanes own one node; lane sub holds features
// 4*sub..4*sub+3. Segment [j, jend) is a multiple of 8 (pad words: w=0).
// ---------------------------------------------------------------------------
__device__ __forceinline__ void gather_grp(const int* __restrict__ bkt,
                                           int j, const int jend,
                                           const char* __restrict__ tbl,
                                           const unsigned sub8,
                                           float& a0, float& a1, float& a2, float& a3) {
#define PAIR_BODY(PX, PY, RA, RB)                                               \
    {                                                                           \
        const unsigned wp = __builtin_amdgcn_perm((unsigned)(PY) >> 17,         \
                                                  (unsigned)(PX) >> 17,         \
                                                  0x05040100u);                 \
        a0 = fdot2u(__builtin_amdgcn_perm((RB).x, (RA).x, 0x05040100u), wp, a0);\
        a1 = fdot2u(__builtin_amdgcn_perm((RB).x, (RA).x, 0x07060302u), wp, a1);\
        a2 = fdot2u(__builtin_amdgcn_perm((RB).y, (RA).y, 0x05040100u), wp, a2);\
        a3 = fdot2u(__builtin_amdgcn_perm((RB).y, (RA).y, 0x07060302u), wp, a3);\
    }
#define TBL(P) (*(const uint2*)(tbl + (((unsigned)(P) & 0x1FFFFu) << 6) + sub8))
    for (; j < jend; j += 8) {
        const int4 p0 = *(const int4*)&bkt[j];       // broadcast within group
        const int4 p1 = *(const int4*)&bkt[j + 4];
        const uint2 r0 = TBL(p0.x);
        const uint2 r1 = TBL(p0.y);
        const uint2 r2 = TBL(p0.z);
        const uint2 r3 = TBL(p0.w);
        const uint2 r4 = TBL(p1.x);
        const uint2 r5 = TBL(p1.y);
        const uint2 r6 = TBL(p1.z);
        const uint2 r7 = TBL(p1.w);
        PAIR_BODY(p0.x, p0.y, r0, r1);
        PAIR_BODY(p0.z, p0.w, r2, r3);
        PAIR_BODY(p1.x, p1.y, r4, r5);
        PAIR_BODY(p1.z, p1.w, r6, r7);
    }
#undef TBL
#undef PAIR_BODY
}

// ---------------------------------------------------------------------------
// Gather 1 + bias1 + ReLU: sequential A-half then B-half (phased table
// slices stay L2-resident). One 8-lane group per node.
// ---------------------------------------------------------------------------
__global__ __launch_bounds__(256) void gather1_kernel(const int* __restrict__ offsA,
                                                      const int* __restrict__ offsB,
                                                      const int* __restrict__ bktA,
                                                      const int* __restrict__ bktB,
                                                      const __half* __restrict__ h1h,
                                                      const float* __restrict__ b1,
                                                      __half* __restrict__ rh) {
    const int tid  = threadIdx.x;
    const int node = blockIdx.x * 32 + (tid >> 3);   // grid exact: 3125*32
    const int sub  = tid & 7;
    const unsigned sub8 = sub * 8;

    float a0 = 0.f, a1 = 0.f, a2 = 0.f, a3 = 0.f;
    gather_grp(bktA, offsA[node], offsA[node + 1], (const char*)h1h, sub8,
               a0, a1, a2, a3);
    gather_grp(bktB, offsB[node], offsB[node + 1], (const char*)h1h, sub8,
               a0, a1, a2, a3);

    const float4 bb = ((const float4*)b1)[sub];
    a0 = fmaxf(a0 + bb.x, 0.f);
    a1 = fmaxf(a1 + bb.y, 0.f);
    a2 = fmaxf(a2 + bb.z, 0.f);
    a3 = fmaxf(a3 + bb.w, 0.f);
    uint2 o;
    *(__half2*)&o.x = __floats2half2_rn(a0, a1);
    *(__half2*)&o.y = __floats2half2_rn(a2, a3);
    *(uint2*)((char*)rh + (size_t)node * 64 + sub8) = o;
}

// ---------------------------------------------------------------------------
// Gather 2 (A then B halves) + W2 + bias2 + log-softmax, fused, group/node.
// ---------------------------------------------------------------------------
__global__ __launch_bounds__(256) void gather2_lsm_kernel(const int* __restrict__ offsA,
                                                          const int* __restrict__ offsB,
                                                          const int* __restrict__ bktA,
                                                          const int* __restrict__ bktB,
                                                          const __half* __restrict__ rh,
                                                          const float* __restrict__ W2,
                                                          const float* __restrict__ b2,
                                                          float* __restrict__ out) {
    __shared__ float W2s[F_HID * F_OUT];   // 5 KB
    __shared__ float sblk[32][F_HID + 1];  // 4.2 KB
    const int tid = threadIdx.x;
    for (int i = tid; i < F_HID * F_OUT; i += 256) W2s[i] = W2[i];
    __syncthreads();

    const int nn   = tid >> 3;
    const int node = blockIdx.x * 32 + nn;           // grid exact: 3125*32
    const int sub  = tid & 7;
    const unsigned sub8 = sub * 8;

    float a0 = 0.f, a1 = 0.f, a2 = 0.f, a3 = 0.f;
    gather_grp(bktA, offsA[node], offsA[node + 1], (const char*)rh, sub8,
               a0, a1, a2, a3);
    gather_grp(bktB, offsB[node], offsB[node + 1], (const char*)rh, sub8,
               a0, a1, a2, a3);

    // stash the node's 32-dim sum (group-local; same-wave ordering suffices)
    sblk[nn][sub * 4 + 0] = a0;
    sblk[nn][sub * 4 + 1] = a1;
    sblk[nn][sub * 4 + 2] = a2;
    sblk[nn][sub * 4 + 3] = a3;

    // transform: lane computes outputs sub, sub+8, ..., sub+32
    float o0 = b2[sub], o1 = b2[sub + 8], o2 = b2[sub + 16],
          o3 = b2[sub + 24], o4 = b2[sub + 32];
    #pragma unroll
    for (int k = 0; k < F_HID; ++k) {
        const float sv = sblk[nn][k];
        const float* wr = &W2s[k * F_OUT + sub];
        o0 += sv * wr[0];
        o1 += sv * wr[8];
        o2 += sv * wr[16];
        o3 += sv * wr[24];
        o4 += sv * wr[32];
    }

    // group softmax over 40 values (5 per lane x 8 lanes)
    float m = fmaxf(fmaxf(fmaxf(o0, o1), fmaxf(o2, o3)), o4);
    m = fmaxf(m, __shfl_xor(m, 1));
    m = fmaxf(m, __shfl_xor(m, 2));
    m = fmaxf(m, __shfl_xor(m, 4));
    float ex = __expf(o0 - m) + __expf(o1 - m) + __expf(o2 - m)
             + __expf(o3 - m) + __expf(o4 - m);
    ex += __shfl_xor(ex, 1);
    ex += __shfl_xor(ex, 2);
    ex += __shfl_xor(ex, 4);
    const float ls = m + __logf(ex);

    float* op = out + (size_t)node * F_OUT + sub;
    op[0]  = o0 - ls;
    op[8]  = o1 - ls;
    op[16] = o2 - ls;
    op[24] = o3 - ls;
    op[32] = o4 - ls;
}

// ---------------------------------------------------------------------------
extern "C" void kernel_launch(void* const* d_in, const int* in_sizes, int n_in,
                              void* d_out, int out_size, void* d_ws, size_t ws_size,
                              hipStream_t stream) {
    const float* x  = (const float*)d_in[0];
    const int*   ei = (const int*)d_in[1];    // [2, E] int32: row 0 = src, row 1 = dst
    const float* ew = (const float*)d_in[2];
    const float* W1 = (const float*)d_in[3];
    const float* b1 = (const float*)d_in[4];
    const float* W2 = (const float*)d_in[5];
    const float* b2 = (const float*)d_in[6];
    float* out = (float*)d_out;

    // Workspace layout (16B-aligned), ~43 MB total.
    char* p = (char*)d_ws;
    size_t off = 0;
    auto alloc = [&](size_t bytes) {
        char* r = p + off;
        off += (bytes + 15) & ~(size_t)15;
        return r;
    };
    int*   gcnt    = (int*)  alloc((size_t)NBLK * NBINS * 4);
    int*   pbase   = (int*)  alloc((size_t)NBLK * NBINS * 4);
    int*   bintot  = (int*)  alloc((size_t)NBINS * 4);
    int*   binbase = (int*)  alloc((size_t)(NBINS + 1) * 4);
    int*   pbtA    = (int*)  alloc((size_t)NBINS * 4);
    int*   pbtB    = (int*)  alloc((size_t)NBINS * 4);
    int*   pbbA    = (int*)  alloc((size_t)(NBINS + 1) * 4);
    int*   pbbB    = (int*)  alloc((size_t)(NBINS + 1) * 4);
    int*   offsIBA = (int*)  alloc((size_t)NBINS * 256 * 4);
    int*   offsIBB = (int*)  alloc((size_t)NBINS * 256 * 4);
    int*   offsA   = (int*)  alloc((size_t)(N_NODES + 1) * 4);
    int*   offsB   = (int*)  alloc((size_t)(N_NODES + 1) * 4);
    int*   bktA    = (int*)  alloc((size_t)CAPH * 4);
    int*   bktB    = (int*)  alloc((size_t)CAPH * 4);
    char*  uni     = (char*) alloc((size_t)N_EDGES * 6);   // stg4 + meta ushort
    int*   stg4    = (int*)uni;
    unsigned short* metag = (unsigned short*)(uni + (size_t)N_EDGES * 4);
    __half* h1h    = (__half*)uni;
    __half* rh     = h1h + (size_t)N_NODES * F_HID;

    // --- CSR build (deterministic bases, no global atomics) ---
    histA_kernel<<<NBLK, 256, 0, stream>>>(ei, gcnt);
    colscan_kernel<<<NBINS, 256, 0, stream>>>(gcnt, pbase, bintot);
    binscan_kernel<<<1, 512, 0, stream>>>(bintot, binbase);
    placeA_kernel<<<NBLK, 256, 0, stream>>>(ei, ew, gcnt, binbase, pbase, stg4, metag);
    partB1_kernel<<<NBINS, 256, 0, stream>>>(binbase, metag, offsIBA, offsIBB, pbtA, pbtB);
    padscan2_kernel<<<1, 512, 0, stream>>>(pbtA, pbtB, pbbA, pbbB, offsA, offsB);
    partB2_kernel<<<NBINS, 256, 0, stream>>>(binbase, stg4, metag, pbbA, pbbB,
                                             offsIBA, offsIBB, offsA, offsB, bktA, bktB);

    // --- Layer 1: h1 = x@W1 (fp16 table); gather A-half then B-half ---
    gemm1_kernel<<<N_NODES / 32, 256, 0, stream>>>(x, W1, h1h);
    gather1_kernel<<<N_NODES / 32, 256, 0, stream>>>(offsA, offsB, bktA, bktB, h1h, b1, rh);

    // --- Layer 2: gather (A,B) + W2 + bias2 + log-softmax, fused ---
    gather2_lsm_kernel<<<N_NODES / 32, 256, 0, stream>>>(offsA, offsB, bktA, bktB, rh, W2, b2, out);
}